// Round 1
// baseline (628.406 us; speedup 1.0000x reference)
//
#include <hip/hip_runtime.h>
#include <math.h>

#define D 64
#define K_CODES 8192
#define M_QUERIES 32768
#define SLICES 8
#define CODES_PER_SLICE (K_CODES / SLICES)   // 1024
#define CHUNK 128                            // codes per LDS chunk
#define QTILE 512                            // queries per block (2 per thread, 256 threads)
#define TAU 1e-2f

// ---------------- K0: per-code squared norms + zero rescue counter ----------
__global__ __launch_bounds__(256) void k0_ee(const float* __restrict__ emb,
                                             float* __restrict__ ws_ee,
                                             int* __restrict__ ws_cnt) {
    int c = blockIdx.x * blockDim.x + threadIdx.x;
    if (c == 0) *ws_cnt = 0;
    if (c < K_CODES) {
        const float4* row = (const float4*)(emb + (size_t)c * D);
        float s0 = 0.f, s1 = 0.f, s2 = 0.f, s3 = 0.f;
#pragma unroll
        for (int k = 0; k < 16; ++k) {
            float4 v = row[k];
            s0 += v.x * v.x; s1 += v.y * v.y; s2 += v.z * v.z; s3 += v.w * v.w;
        }
        ws_ee[c] = (s0 + s1) + (s2 + s3);
    }
}

// ---------------- K1: fp32 top-2 argmin over one code slice ----------------
__global__ __launch_bounds__(256) void k1_argmin(const float* __restrict__ z,
                                                 const float* __restrict__ emb,
                                                 const float* __restrict__ ws_ee,
                                                 float4* __restrict__ ws_part) {
    __shared__ float4 se[CHUNK][16];   // 32 KB code tile
    __shared__ float  see[CHUNK];

    const int tid   = threadIdx.x;
    const int qbase = blockIdx.x * QTILE;
    const int slice = blockIdx.y;
    const int q0 = qbase + tid;
    const int q1 = qbase + 256 + tid;

    // Load 2 query rows into registers (static indices -> VGPRs)
    float4 z0[16], z1[16];
    const float4* z0p = (const float4*)(z + (size_t)q0 * D);
    const float4* z1p = (const float4*)(z + (size_t)q1 * D);
#pragma unroll
    for (int k = 0; k < 16; ++k) { z0[k] = z0p[k]; z1[k] = z1p[k]; }

    float a0=0,a1=0,a2=0,a3=0, b0=0,b1=0,b2=0,b3=0;
#pragma unroll
    for (int k = 0; k < 16; ++k) {
        a0 += z0[k].x*z0[k].x; a1 += z0[k].y*z0[k].y; a2 += z0[k].z*z0[k].z; a3 += z0[k].w*z0[k].w;
        b0 += z1[k].x*z1[k].x; b1 += z1[k].y*z1[k].y; b2 += z1[k].z*z1[k].z; b3 += z1[k].w*z1[k].w;
    }
    const float zz0 = (a0+a1)+(a2+a3);
    const float zz1 = (b0+b1)+(b2+b3);

    float m1_0 = 1e30f, m2_0 = 1e30f; int i_0 = 0x7fffffff;
    float m1_1 = 1e30f, m2_1 = 1e30f; int i_1 = 0x7fffffff;

    const int code0 = slice * CODES_PER_SLICE;
    for (int ch = 0; ch < CODES_PER_SLICE; ch += CHUNK) {
        __syncthreads();
        // cooperative stage: 128 codes * 64 floats = 2048 float4
        const float4* src = (const float4*)(emb + (size_t)(code0 + ch) * D);
#pragma unroll
        for (int k = 0; k < 8; ++k)
            ((float4*)se)[tid + k * 256] = src[tid + k * 256];
        if (tid < CHUNK) see[tid] = ws_ee[code0 + ch + tid];
        __syncthreads();

        for (int c = 0; c < CHUNK; ++c) {
            float d00=0,d01=0,d02=0,d03=0;
            float d10=0,d11=0,d12=0,d13=0;
#pragma unroll
            for (int k = 0; k < 16; ++k) {
                float4 e = se[c][k];   // wave-uniform address -> broadcast, no conflicts
                d00 = fmaf(e.x, z0[k].x, d00); d01 = fmaf(e.y, z0[k].y, d01);
                d02 = fmaf(e.z, z0[k].z, d02); d03 = fmaf(e.w, z0[k].w, d03);
                d10 = fmaf(e.x, z1[k].x, d10); d11 = fmaf(e.y, z1[k].y, d11);
                d12 = fmaf(e.z, z1[k].z, d12); d13 = fmaf(e.w, z1[k].w, d13);
            }
            const float ee = see[c];
            const float dot0 = (d00 + d01) + (d02 + d03);
            const float dot1 = (d10 + d11) + (d12 + d13);
            const float d2_0 = fmaf(-2.0f, dot0, zz0 + ee);
            const float d2_1 = fmaf(-2.0f, dot1, zz1 + ee);
            const int cg = code0 + ch + c;
            // strict < keeps first occurrence (numpy argmin tie-break)
            if (d2_0 < m1_0) { m2_0 = m1_0; m1_0 = d2_0; i_0 = cg; } else { m2_0 = fminf(m2_0, d2_0); }
            if (d2_1 < m1_1) { m2_1 = m1_1; m1_1 = d2_1; i_1 = cg; } else { m2_1 = fminf(m2_1, d2_1); }
        }
    }
    ws_part[(size_t)q0 * SLICES + slice] = make_float4(m1_0, m2_0, __int_as_float(i_0), 0.f);
    ws_part[(size_t)q1 * SLICES + slice] = make_float4(m1_1, m2_1, __int_as_float(i_1), 0.f);
}

// ---------------- K1b: merge slices, flag near-ties ------------------------
__global__ __launch_bounds__(256) void k1b_merge(const float4* __restrict__ ws_part,
                                                 int* __restrict__ ws_idx,
                                                 float* __restrict__ ws_d2,
                                                 int* __restrict__ ws_cnt,
                                                 int* __restrict__ ws_list) {
    int q = blockIdx.x * blockDim.x + threadIdx.x;
    if (q >= M_QUERIES) return;
    float m1 = 1e30f, m2 = 1e30f; int i1 = 0x7fffffff;
#pragma unroll
    for (int s = 0; s < SLICES; ++s) {
        float4 p = ws_part[(size_t)q * SLICES + s];
        float v1 = p.x, v2 = p.y; int vi = __float_as_int(p.z);
        if (v1 < m1 || (v1 == m1 && vi < i1)) { m2 = fminf(m1, v2); m1 = v1; i1 = vi; }
        else                                  { m2 = fminf(m2, v1); }
    }
    ws_idx[q] = i1;
    ws_d2[q]  = m1;
    if (m2 - m1 < TAU) {       // near-tie: resolve in fp64 (also catches exact ties)
        int r = atomicAdd(ws_cnt, 1);
        ws_list[r] = q;
    }
}

// ---------------- K2: fp64 exact rescan for flagged queries ----------------
__global__ __launch_bounds__(256) void k2_rescue(const float* __restrict__ z,
                                                 const float* __restrict__ emb,
                                                 const int* __restrict__ ws_cnt,
                                                 const int* __restrict__ ws_list,
                                                 int* __restrict__ ws_idx,
                                                 float* __restrict__ ws_d2) {
    __shared__ float  zrow[D];
    __shared__ double rv[256];
    __shared__ int    ri[256];
    const int cnt = *ws_cnt;
    for (int r = blockIdx.x; r < cnt; r += gridDim.x) {
        const int q = ws_list[r];
        __syncthreads();
        if (threadIdx.x < D) zrow[threadIdx.x] = z[(size_t)q * D + threadIdx.x];
        __syncthreads();
        double best = 1e300; int bi = 0x7fffffff;
        for (int c = threadIdx.x; c < K_CODES; c += 256) {
            const float4* er = (const float4*)(emb + (size_t)c * D);
            double acc = 0.0;
#pragma unroll
            for (int k = 0; k < 16; ++k) {
                float4 e = er[k];
                double d0 = (double)zrow[4*k+0] - (double)e.x;
                double d1 = (double)zrow[4*k+1] - (double)e.y;
                double d2 = (double)zrow[4*k+2] - (double)e.z;
                double d3 = (double)zrow[4*k+3] - (double)e.w;
                acc += d0*d0 + d1*d1 + d2*d2 + d3*d3;
            }
            if (acc < best) { best = acc; bi = c; }   // ascending c -> first occurrence
        }
        rv[threadIdx.x] = best; ri[threadIdx.x] = bi;
        __syncthreads();
        for (int s = 128; s > 0; s >>= 1) {
            if (threadIdx.x < s) {
                double ov = rv[threadIdx.x + s]; int oi = ri[threadIdx.x + s];
                if (ov < rv[threadIdx.x] || (ov == rv[threadIdx.x] && oi < ri[threadIdx.x])) {
                    rv[threadIdx.x] = ov; ri[threadIdx.x] = oi;
                }
            }
            __syncthreads();
        }
        if (threadIdx.x == 0) { ws_idx[q] = ri[0]; ws_d2[q] = (float)rv[0]; }
        __syncthreads();
    }
}

// ---------------- K3: gather z_q, emit idx as float ------------------------
__global__ __launch_bounds__(256) void k3_gather(const float* __restrict__ emb,
                                                 const int* __restrict__ ws_idx,
                                                 float* __restrict__ out) {
    int g = blockIdx.x * blockDim.x + threadIdx.x;   // 0 .. M*D
    int q = g >> 6, d = g & 63;
    int id = ws_idx[q];
    out[g] = emb[(size_t)id * D + d];
    if (d == 0) out[(size_t)M_QUERIES * D + q] = (float)id;
}

// ---------------- K4: loss = 1.25 * mean(d2) -------------------------------
__global__ __launch_bounds__(256) void k4_loss(const float* __restrict__ ws_d2,
                                               float* __restrict__ out) {
    __shared__ double sb[256];
    double s = 0.0;
    for (int q = threadIdx.x; q < M_QUERIES; q += 256) s += (double)ws_d2[q];
    sb[threadIdx.x] = s;
    __syncthreads();
    for (int st = 128; st > 0; st >>= 1) {
        if (threadIdx.x < st) sb[threadIdx.x] += sb[threadIdx.x + st];
        __syncthreads();
    }
    if (threadIdx.x == 0)
        out[(size_t)M_QUERIES * D + M_QUERIES] =
            (float)(1.25 * sb[0] / (double)((size_t)M_QUERIES * D));
}

extern "C" void kernel_launch(void* const* d_in, const int* in_sizes, int n_in,
                              void* d_out, int out_size, void* d_ws, size_t ws_size,
                              hipStream_t stream) {
    const float* z   = (const float*)d_in[0];
    const float* emb = (const float*)d_in[1];
    float* out = (float*)d_out;
    char*  ws  = (char*)d_ws;

    // workspace layout (~4.5 MB total)
    float*  ws_ee   = (float*)(ws);                                   // 32 KB
    float4* ws_part = (float4*)(ws + 32768);                          // 4 MB
    int*    ws_idx  = (int*)(ws + 32768 + 4194304);                   // 128 KB
    float*  ws_d2   = (float*)(ws + 32768 + 4194304 + 131072);        // 128 KB
    int*    ws_cnt  = (int*)(ws + 32768 + 4194304 + 262144);          // 16 B
    int*    ws_list = (int*)(ws + 32768 + 4194304 + 262144 + 16);     // 128 KB

    k0_ee<<<K_CODES / 256, 256, 0, stream>>>(emb, ws_ee, ws_cnt);

    dim3 g1(M_QUERIES / QTILE, SLICES);
    k1_argmin<<<g1, 256, 0, stream>>>(z, emb, ws_ee, ws_part);

    k1b_merge<<<M_QUERIES / 256, 256, 0, stream>>>(ws_part, ws_idx, ws_d2, ws_cnt, ws_list);

    k2_rescue<<<256, 256, 0, stream>>>(z, emb, ws_cnt, ws_list, ws_idx, ws_d2);

    k3_gather<<<(M_QUERIES * D) / 256, 256, 0, stream>>>(emb, ws_idx, out);

    k4_loss<<<1, 256, 0, stream>>>(ws_d2, out);
}

// Round 2
// 409.995 us; speedup vs baseline: 1.5327x; 1.5327x over previous
//
#include <hip/hip_runtime.h>
#include <hip/hip_bf16.h>
#include <math.h>

#define D 64
#define K_CODES 8192
#define M_QUERIES 32768
#define CHUNK 128
#define NCHUNK (K_CODES / CHUNK)    // 64
#define QPB 128                      // queries per block = 4 waves * 32
#define TAU_V 8e-3f                  // v-units; d2 gap = 2*v gap

typedef __attribute__((ext_vector_type(8))) short bf16x8;
typedef __attribute__((ext_vector_type(4))) float f32x4;

__device__ __forceinline__ unsigned short f2bf(float x) {
    __hip_bfloat16 h = __float2bfloat16(x);
    return *reinterpret_cast<unsigned short*>(&h);
}
__device__ __forceinline__ float bf2f(unsigned short s) {
    __hip_bfloat16 h;
    *reinterpret_cast<unsigned short*>(&h) = s;
    return __bfloat162float(h);
}

// ---- K0: split emb into bf16 hi/lo, compute 0.5*||e||^2, zero rescue cnt ----
__global__ __launch_bounds__(256) void k0_split(const float* __restrict__ emb,
                                                unsigned short* __restrict__ e_hi,
                                                unsigned short* __restrict__ e_lo,
                                                float* __restrict__ halfee,
                                                int* __restrict__ ws_cnt) {
    const int wid = threadIdx.x >> 6, l = threadIdx.x & 63;
    const int c = blockIdx.x * 4 + wid;
    if (c == 0 && l == 0) *ws_cnt = 0;
    float e = emb[(size_t)c * D + l];
    unsigned short h = f2bf(e);
    float r = e - bf2f(h);
    e_hi[(size_t)c * D + l] = h;
    e_lo[(size_t)c * D + l] = f2bf(r);
    float s = e * e;
#pragma unroll
    for (int m = 1; m < 64; m <<= 1) s += __shfl_xor(s, m);
    if (l == 0) halfee[c] = 0.5f * s;
}

// ---- K1: MFMA scoring (v = 0.5ee - z.e via bf16-split), fused top-2 argmin ----
__global__ __launch_bounds__(256, 1) void k1_mfma(const float* __restrict__ z,
                                                  const unsigned short* __restrict__ e_hi,
                                                  const unsigned short* __restrict__ e_lo,
                                                  const float* __restrict__ halfee,
                                                  int* __restrict__ ws_idx,
                                                  int* __restrict__ ws_cnt,
                                                  int* __restrict__ ws_list) {
    __shared__ unsigned short ldshi[2][CHUNK * 64];
    __shared__ unsigned short ldslo[2][CHUNK * 64];
    __shared__ float ldshe[2][CHUNK];

    const int tid = threadIdx.x;
    const int wid = tid >> 6;
    const int l   = tid & 63;
    const int l15 = l & 15, l16 = l >> 4, l7 = l & 7, l8 = l >> 3;

    // Load this wave's 32 queries; split into negated bf16 hi/lo B-fragments.
    const int qw0 = blockIdx.x * QPB + wid * 32;
    bf16x8 qh[2][2], ql[2][2];
#pragma unroll
    for (int qt = 0; qt < 2; ++qt)
#pragma unroll
        for (int kk = 0; kk < 2; ++kk) {
            const float* src = z + (size_t)(qw0 + qt * 16 + l15) * D + kk * 32 + l16 * 8;
            float4 f0 = *(const float4*)(src);
            float4 f1 = *(const float4*)(src + 4);
            float f[8] = {f0.x, f0.y, f0.z, f0.w, f1.x, f1.y, f1.z, f1.w};
            bf16x8 h, lo;
#pragma unroll
            for (int j = 0; j < 8; ++j) {
                float x = -f[j];
                unsigned short hh = f2bf(x);
                float r = x - bf2f(hh);
                h[j]  = (short)hh;
                lo[j] = (short)f2bf(r);
            }
            qh[qt][kk] = h;
            ql[qt][kk] = lo;
        }

    float m1[2] = {1e30f, 1e30f}, m2[2] = {1e30f, 1e30f};
    int   i1[2] = {0x7fffffff, 0x7fffffff};
    float4 rh[4], rl[4], rhe;

#define ISSUE_LOADS(c1)                                                          \
    {                                                                            \
        const char* bhi = (const char*)e_hi + (size_t)(c1) * 16384;              \
        const char* blo = (const char*)e_lo + (size_t)(c1) * 16384;              \
        _Pragma("unroll") for (int p = 0; p < 4; ++p) {                          \
            int off = (wid * 32 + p * 8 + l8) * 128 + l7 * 16;                   \
            rh[p] = *(const float4*)(bhi + off);                                 \
            rl[p] = *(const float4*)(blo + off);                                 \
        }                                                                        \
        if (wid == 3 && l < 32)                                                  \
            rhe = *(const float4*)((const char*)halfee + (size_t)(c1) * 512 + l * 16); \
    }

#define WRITE_LDS(buf)                                                           \
    {                                                                            \
        _Pragma("unroll") for (int p = 0; p < 4; ++p) {                          \
            int r   = wid * 32 + p * 8 + l8;                                     \
            int off = r * 128 + ((l7 ^ l8)) * 16;                                \
            *(float4*)((char*)ldshi[buf] + off) = rh[p];                         \
            *(float4*)((char*)ldslo[buf] + off) = rl[p];                         \
        }                                                                        \
        if (wid == 3 && l < 32) *(float4*)((char*)ldshe[buf] + l * 16) = rhe;    \
    }

#define COMPUTE(bufc, cbase)                                                     \
    {                                                                            \
        const unsigned short* bh  = ldshi[bufc];                                 \
        const unsigned short* bl  = ldslo[bufc];                                 \
        const float*          bhe = ldshe[bufc];                                 \
        _Pragma("unroll") for (int ct = 0; ct < 8; ++ct) {                       \
            int rowb = (ct * 16 + l15) * 128;                                    \
            bf16x8 ah0 = *(const bf16x8*)((const char*)bh + rowb + ((l16 ^ l7) * 16));       \
            bf16x8 ah1 = *(const bf16x8*)((const char*)bh + rowb + (((4 + l16) ^ l7) * 16)); \
            bf16x8 al0 = *(const bf16x8*)((const char*)bl + rowb + ((l16 ^ l7) * 16));       \
            bf16x8 al1 = *(const bf16x8*)((const char*)bl + rowb + (((4 + l16) ^ l7) * 16)); \
            f32x4 he = *(const f32x4*)(bhe + ct * 16 + l16 * 4);                 \
            _Pragma("unroll") for (int qt = 0; qt < 2; ++qt) {                   \
                f32x4 va = he;                                                   \
                f32x4 vb = {0.f, 0.f, 0.f, 0.f};                                 \
                va = __builtin_amdgcn_mfma_f32_16x16x32_bf16(ah0, qh[qt][0], va, 0, 0, 0); \
                vb = __builtin_amdgcn_mfma_f32_16x16x32_bf16(ah1, qh[qt][1], vb, 0, 0, 0); \
                va = __builtin_amdgcn_mfma_f32_16x16x32_bf16(ah0, ql[qt][0], va, 0, 0, 0); \
                vb = __builtin_amdgcn_mfma_f32_16x16x32_bf16(ah1, ql[qt][1], vb, 0, 0, 0); \
                va = __builtin_amdgcn_mfma_f32_16x16x32_bf16(al0, qh[qt][0], va, 0, 0, 0); \
                vb = __builtin_amdgcn_mfma_f32_16x16x32_bf16(al1, qh[qt][1], vb, 0, 0, 0); \
                int cb = (cbase) + ct * 16 + l16 * 4;                            \
                _Pragma("unroll") for (int j = 0; j < 4; ++j) {                  \
                    float v     = va[j] + vb[j];                                 \
                    bool  lt    = v < m1[qt];                                    \
                    float cand2 = lt ? m1[qt] : v;                               \
                    m2[qt] = fminf(m2[qt], cand2);                               \
                    i1[qt] = lt ? (cb + j) : i1[qt];                             \
                    m1[qt] = fminf(m1[qt], v);                                   \
                }                                                                \
            }                                                                    \
        }                                                                        \
    }

    ISSUE_LOADS(0);
    WRITE_LDS(0);
    __syncthreads();
    for (int c = 0; c < NCHUNK; ++c) {
        const int cur = c & 1;
        if (c + 1 < NCHUNK) ISSUE_LOADS(c + 1);
        COMPUTE(cur, c * CHUNK);
        __syncthreads();
        if (c + 1 < NCHUNK) WRITE_LDS(cur ^ 1);
        __syncthreads();
    }

    // cross-lane merge: lanes {q, q+16, q+32, q+48} hold disjoint code streams
#pragma unroll
    for (int qt = 0; qt < 2; ++qt) {
        float a1 = m1[qt], a2 = m2[qt];
        int   ai = i1[qt];
#pragma unroll
        for (int mask = 16; mask <= 32; mask <<= 1) {
            float o1 = __shfl_xor(a1, mask);
            float o2 = __shfl_xor(a2, mask);
            int   oi = __shfl_xor(ai, mask);
            bool  take = (o1 < a1) || (o1 == a1 && oi < ai);
            float n2   = take ? fminf(o2, a1) : fminf(a2, o1);
            a1 = take ? o1 : a1;
            ai = take ? oi : ai;
            a2 = n2;
        }
        if (l < 16) {
            int q = qw0 + qt * 16 + l15;
            ws_idx[q] = ai;
            if (a2 - a1 < TAU_V) {
                int r = atomicAdd(ws_cnt, 1);
                ws_list[r] = q;
            }
        }
    }
#undef ISSUE_LOADS
#undef WRITE_LDS
#undef COMPUTE
}

// ---- K2: fp64 exact rescan for near-tie queries ----
__global__ __launch_bounds__(256) void k2_rescue(const float* __restrict__ z,
                                                 const float* __restrict__ emb,
                                                 const int* __restrict__ ws_cnt,
                                                 const int* __restrict__ ws_list,
                                                 int* __restrict__ ws_idx) {
    __shared__ float  zrow[D];
    __shared__ double rv[256];
    __shared__ int    ri[256];
    const int cnt = *ws_cnt;
    for (int r = blockIdx.x; r < cnt; r += gridDim.x) {
        const int q = ws_list[r];
        __syncthreads();
        if (threadIdx.x < D) zrow[threadIdx.x] = z[(size_t)q * D + threadIdx.x];
        __syncthreads();
        double best = 1e300;
        int    bi   = 0x7fffffff;
        for (int c = threadIdx.x; c < K_CODES; c += 256) {
            const float4* er = (const float4*)(emb + (size_t)c * D);
            double acc = 0.0;
#pragma unroll
            for (int k = 0; k < 16; ++k) {
                float4 e  = er[k];
                double d0 = (double)zrow[4 * k + 0] - (double)e.x;
                double d1 = (double)zrow[4 * k + 1] - (double)e.y;
                double d2 = (double)zrow[4 * k + 2] - (double)e.z;
                double d3 = (double)zrow[4 * k + 3] - (double)e.w;
                acc += d0 * d0 + d1 * d1 + d2 * d2 + d3 * d3;
            }
            if (acc < best) { best = acc; bi = c; }
        }
        rv[threadIdx.x] = best;
        ri[threadIdx.x] = bi;
        __syncthreads();
        for (int s = 128; s > 0; s >>= 1) {
            if (threadIdx.x < s) {
                double ov = rv[threadIdx.x + s];
                int    oi = ri[threadIdx.x + s];
                if (ov < rv[threadIdx.x] || (ov == rv[threadIdx.x] && oi < ri[threadIdx.x])) {
                    rv[threadIdx.x] = ov;
                    ri[threadIdx.x] = oi;
                }
            }
            __syncthreads();
        }
        if (threadIdx.x == 0) ws_idx[q] = ri[0];
        __syncthreads();
    }
}

// ---- K3: gather z_q, emit idx as float, per-block loss partials ----
__global__ __launch_bounds__(256) void k3_gather(const float* __restrict__ emb,
                                                 const float* __restrict__ z,
                                                 const int* __restrict__ ws_idx,
                                                 float* __restrict__ out,
                                                 float* __restrict__ partial) {
    __shared__ float sb[256];
    int g = blockIdx.x * 256 + threadIdx.x;
    int q = g >> 6, d = g & 63;
    int id = ws_idx[q];
    float e = emb[(size_t)id * D + d];
    out[g] = e;
    if (d == 0) out[(size_t)M_QUERIES * D + q] = (float)id;
    float df = e - z[g];
    sb[threadIdx.x] = df * df;
    __syncthreads();
    for (int s = 128; s > 0; s >>= 1) {
        if (threadIdx.x < s) sb[threadIdx.x] += sb[threadIdx.x + s];
        __syncthreads();
    }
    if (threadIdx.x == 0) partial[blockIdx.x] = sb[0];
}

// ---- K4: final loss reduce ----
__global__ __launch_bounds__(256) void k4_loss(const float* __restrict__ partial,
                                               float* __restrict__ out) {
    __shared__ double sb[256];
    double s = 0.0;
    for (int i = threadIdx.x; i < (M_QUERIES * D) / 256; i += 256) s += (double)partial[i];
    sb[threadIdx.x] = s;
    __syncthreads();
    for (int st = 128; st > 0; st >>= 1) {
        if (threadIdx.x < st) sb[threadIdx.x] += sb[threadIdx.x + st];
        __syncthreads();
    }
    if (threadIdx.x == 0)
        out[(size_t)M_QUERIES * D + M_QUERIES] =
            (float)(1.25 * sb[0] / (double)((size_t)M_QUERIES * D));
}

extern "C" void kernel_launch(void* const* d_in, const int* in_sizes, int n_in,
                              void* d_out, int out_size, void* d_ws, size_t ws_size,
                              hipStream_t stream) {
    const float* z   = (const float*)d_in[0];
    const float* emb = (const float*)d_in[1];
    float* out = (float*)d_out;
    char*  ws  = (char*)d_ws;

    unsigned short* e_hi    = (unsigned short*)(ws);                   // 1 MB
    unsigned short* e_lo    = (unsigned short*)(ws + 1048576);         // 1 MB
    float*          halfee  = (float*)(ws + 2097152);                  // 32 KB
    int*            ws_idx  = (int*)(ws + 2129920);                    // 128 KB
    int*            ws_cnt  = (int*)(ws + 2260992);                    // 64 B
    int*            ws_list = (int*)(ws + 2261056);                    // 128 KB
    float*          partial = (float*)(ws + 2392128);                  // 32 KB

    k0_split<<<K_CODES / 4, 256, 0, stream>>>(emb, e_hi, e_lo, halfee, ws_cnt);
    k1_mfma<<<M_QUERIES / QPB, 256, 0, stream>>>(z, e_hi, e_lo, halfee,
                                                 ws_idx, ws_cnt, ws_list);
    k2_rescue<<<256, 256, 0, stream>>>(z, emb, ws_cnt, ws_list, ws_idx);
    k3_gather<<<(M_QUERIES * D) / 256, 256, 0, stream>>>(emb, z, ws_idx, out, partial);
    k4_loss<<<1, 256, 0, stream>>>(partial, out);
}

// Round 3
// 308.131 us; speedup vs baseline: 2.0394x; 1.3306x over previous
//
#include <hip/hip_runtime.h>
#include <hip/hip_bf16.h>
#include <math.h>

#define D 64
#define K_CODES 8192
#define M_QUERIES 32768
#define SLICES 4
#define CODES_PER_SLICE (K_CODES / SLICES)  // 2048
#define CHUNK 64
#define NCHUNK (CODES_PER_SLICE / CHUNK)    // 32
#define QPB 128                              // queries per block = 4 waves * 32
#define TAU_V 8e-3f                          // gap threshold in v units (d2 gap = 2*v gap)

typedef __attribute__((ext_vector_type(8))) short bf16x8;
typedef __attribute__((ext_vector_type(4))) float f32x4;

__device__ __forceinline__ unsigned short f2bf(float x) {
    __hip_bfloat16 h = __float2bfloat16(x);
    return *reinterpret_cast<unsigned short*>(&h);
}
__device__ __forceinline__ float bf2f(unsigned short s) {
    __hip_bfloat16 h;
    *reinterpret_cast<unsigned short*>(&h) = s;
    return __bfloat162float(h);
}

// ---- K0: split emb into bf16 hi/lo, he' = 0.5*||e||^2 + 128, zero counter ----
__global__ __launch_bounds__(256) void k0_split(const float* __restrict__ emb,
                                                unsigned short* __restrict__ e_hi,
                                                unsigned short* __restrict__ e_lo,
                                                float* __restrict__ halfee,
                                                int* __restrict__ ws_cnt) {
    const int wid = threadIdx.x >> 6, l = threadIdx.x & 63;
    const int c = blockIdx.x * 4 + wid;
    if (c == 0 && l == 0) *ws_cnt = 0;
    float e = emb[(size_t)c * D + l];
    unsigned short h = f2bf(e);
    float r = e - bf2f(h);
    e_hi[(size_t)c * D + l] = h;
    e_lo[(size_t)c * D + l] = f2bf(r);
    float s = e * e;
#pragma unroll
    for (int m = 1; m < 64; m <<= 1) s += __shfl_xor(s, m);
    if (l == 0) halfee[c] = 0.5f * s + 128.0f;
}

// ---- K1: MFMA scoring v = he' - z.e (bf16 split), packed top-2 argmin ----
__global__ __launch_bounds__(256, 4) void k1_mfma(const float* __restrict__ z,
                                                  const unsigned short* __restrict__ e_hi,
                                                  const unsigned short* __restrict__ e_lo,
                                                  const float* __restrict__ halfee,
                                                  float4* __restrict__ ws_part) {
    __shared__ unsigned short ldshi[2][CHUNK * 64];
    __shared__ unsigned short ldslo[2][CHUNK * 64];
    __shared__ float ldshe[2][CHUNK];

    const int tid = threadIdx.x;
    const int wid = tid >> 6;
    const int l   = tid & 63;
    const int l15 = l & 15, l16 = l >> 4;
    const int slice = blockIdx.y;
    const int cslice0 = slice * CODES_PER_SLICE;

    // this wave's 32 queries -> negated bf16 hi/lo B-fragments in regs
    const int qw0 = blockIdx.x * QPB + wid * 32;
    bf16x8 qh[2][2], ql[2][2];
#pragma unroll
    for (int qt = 0; qt < 2; ++qt)
#pragma unroll
        for (int kk = 0; kk < 2; ++kk) {
            const float* src = z + (size_t)(qw0 + qt * 16 + l15) * D + kk * 32 + l16 * 8;
            float4 f0 = *(const float4*)(src);
            float4 f1 = *(const float4*)(src + 4);
            float f[8] = {f0.x, f0.y, f0.z, f0.w, f1.x, f1.y, f1.z, f1.w};
            bf16x8 h, lo;
#pragma unroll
            for (int j = 0; j < 8; ++j) {
                float x = -f[j];
                unsigned short hh = f2bf(x);
                float r = x - bf2f(hh);
                h[j]  = (short)hh;
                lo[j] = (short)f2bf(r);
            }
            qh[qt][kk] = h;
            ql[qt][kk] = lo;
        }

    float g1[2] = {1e30f, 1e30f}, g2[2] = {1e30f, 1e30f};
    int   gi[2] = {0x7fffffff, 0x7fffffff};
    float4 rh[2], rl[2], rhe;

#define ISSUE_LOADS(c1)                                                          \
    {                                                                            \
        const char* bhi = (const char*)e_hi + (size_t)(cslice0 + (c1) * CHUNK) * 128; \
        const char* blo = (const char*)e_lo + (size_t)(cslice0 + (c1) * CHUNK) * 128; \
        _Pragma("unroll") for (int p = 0; p < 2; ++p) {                          \
            int idx = p * 256 + tid;                                             \
            rh[p] = *(const float4*)(bhi + idx * 16);                            \
            rl[p] = *(const float4*)(blo + idx * 16);                            \
        }                                                                        \
        if (tid < 16)                                                            \
            rhe = *(const float4*)((const char*)halfee +                         \
                                   (size_t)(cslice0 + (c1) * CHUNK) * 4 + tid * 16); \
    }

#define WRITE_LDS(buf)                                                           \
    {                                                                            \
        _Pragma("unroll") for (int p = 0; p < 2; ++p) {                          \
            int idx = p * 256 + tid;                                             \
            int r = idx >> 3, cc = idx & 7;                                      \
            int off = r * 128 + (cc ^ (r & 7)) * 16;                             \
            *(float4*)((char*)ldshi[buf] + off) = rh[p];                         \
            *(float4*)((char*)ldslo[buf] + off) = rl[p];                         \
        }                                                                        \
        if (tid < 16) *(float4*)((char*)ldshe[buf] + tid * 16) = rhe;            \
    }

#define COMPUTE(bufc, cbase)                                                     \
    {                                                                            \
        const char* bh  = (const char*)ldshi[bufc];                              \
        const char* bl  = (const char*)ldslo[bufc];                              \
        const float* bhe = ldshe[bufc];                                          \
        float m1p[2] = {1e30f, 1e30f}, m2p[2] = {1e30f, 1e30f};                  \
        _Pragma("unroll") for (int ct = 0; ct < 4; ++ct) {                       \
            int R0 = ct * 16 + l15;                                              \
            int rowb = R0 * 128;                                                 \
            int sw0 = ((l16)     ^ (R0 & 7)) * 16;                               \
            int sw1 = ((4 + l16) ^ (R0 & 7)) * 16;                               \
            bf16x8 ah0 = *(const bf16x8*)(bh + rowb + sw0);                      \
            bf16x8 ah1 = *(const bf16x8*)(bh + rowb + sw1);                      \
            bf16x8 al0 = *(const bf16x8*)(bl + rowb + sw0);                      \
            bf16x8 al1 = *(const bf16x8*)(bl + rowb + sw1);                      \
            f32x4 he = *(const f32x4*)(bhe + ct * 16 + l16 * 4);                 \
            _Pragma("unroll") for (int qt = 0; qt < 2; ++qt) {                   \
                f32x4 va;                                                        \
                va = __builtin_amdgcn_mfma_f32_16x16x32_bf16(ah0, qh[qt][0], he, 0, 0, 0); \
                va = __builtin_amdgcn_mfma_f32_16x16x32_bf16(ah1, qh[qt][1], va, 0, 0, 0); \
                va = __builtin_amdgcn_mfma_f32_16x16x32_bf16(ah0, ql[qt][0], va, 0, 0, 0); \
                va = __builtin_amdgcn_mfma_f32_16x16x32_bf16(ah1, ql[qt][1], va, 0, 0, 0); \
                va = __builtin_amdgcn_mfma_f32_16x16x32_bf16(al0, qh[qt][0], va, 0, 0, 0); \
                va = __builtin_amdgcn_mfma_f32_16x16x32_bf16(al1, qh[qt][1], va, 0, 0, 0); \
                _Pragma("unroll") for (int j = 0; j < 4; ++j) {                  \
                    int pos = ct * 4 + j;                                        \
                    float vp = __int_as_float((__float_as_int(va[j]) & 0xFFFFFFF0) | pos); \
                    m2p[qt] = __builtin_amdgcn_fmed3f(vp, m1p[qt], m2p[qt]);     \
                    m1p[qt] = fminf(m1p[qt], vp);                                \
                }                                                                \
            }                                                                    \
        }                                                                        \
        _Pragma("unroll") for (int qt = 0; qt < 2; ++qt) {                       \
            float v1 = m1p[qt];                                                  \
            int   p1 = __float_as_int(v1) & 15;                                  \
            int code = (cbase) + l16 * 4 + ((p1 >> 2) << 4) + (p1 & 3);          \
            bool lt = v1 < g1[qt];                                               \
            g2[qt] = fminf(lt ? g1[qt] : g2[qt], lt ? m2p[qt] : v1);             \
            g1[qt] = lt ? v1 : g1[qt];                                           \
            gi[qt] = lt ? code : gi[qt];                                         \
        }                                                                        \
    }

    ISSUE_LOADS(0);
    WRITE_LDS(0);
    __syncthreads();
    for (int c = 0; c < NCHUNK; ++c) {
        const int cur = c & 1;
        if (c + 1 < NCHUNK) ISSUE_LOADS(c + 1);
        COMPUTE(cur, cslice0 + c * CHUNK);
        __syncthreads();
        if (c + 1 < NCHUNK) WRITE_LDS(cur ^ 1);
        __syncthreads();
    }

    // lanes {l15, l15+16, l15+32, l15+48} share a query, hold disjoint codes
#pragma unroll
    for (int qt = 0; qt < 2; ++qt) {
        float a1 = g1[qt], a2 = g2[qt];
        int   ai = gi[qt];
#pragma unroll
        for (int mask = 16; mask <= 32; mask <<= 1) {
            float o1 = __shfl_xor(a1, mask);
            float o2 = __shfl_xor(a2, mask);
            int   oi = __shfl_xor(ai, mask);
            bool  take = (o1 < a1) || (o1 == a1 && oi < ai);
            float n2   = take ? fminf(o2, a1) : fminf(a2, o1);
            a1 = take ? o1 : a1;
            ai = take ? oi : ai;
            a2 = n2;
        }
        if (l < 16) {
            int q = qw0 + qt * 16 + l15;
            ws_part[(size_t)q * SLICES + slice] =
                make_float4(a1, a2, __int_as_float(ai), 0.f);
        }
    }
#undef ISSUE_LOADS
#undef WRITE_LDS
#undef COMPUTE
}

// ---- K1b: merge slices, flag near-ties ----
__global__ __launch_bounds__(256) void k1b_merge(const float4* __restrict__ ws_part,
                                                 int* __restrict__ ws_idx,
                                                 int* __restrict__ ws_cnt,
                                                 int* __restrict__ ws_list) {
    int q = blockIdx.x * blockDim.x + threadIdx.x;
    float m1 = 1e30f, m2 = 1e30f;
    int   i1 = 0x7fffffff;
#pragma unroll
    for (int s = 0; s < SLICES; ++s) {
        float4 p = ws_part[(size_t)q * SLICES + s];
        float v1 = p.x, v2 = p.y;
        int   vi = __float_as_int(p.z);
        if (v1 < m1 || (v1 == m1 && vi < i1)) { m2 = fminf(m1, v2); m1 = v1; i1 = vi; }
        else                                  { m2 = fminf(m2, v1); }
    }
    ws_idx[q] = i1;
    if (m2 - m1 < TAU_V) {
        int r = atomicAdd(ws_cnt, 1);
        ws_list[r] = q;
    }
}

// ---- K2: fp64 exact rescan for near-tie queries ----
__global__ __launch_bounds__(256) void k2_rescue(const float* __restrict__ z,
                                                 const float* __restrict__ emb,
                                                 const int* __restrict__ ws_cnt,
                                                 const int* __restrict__ ws_list,
                                                 int* __restrict__ ws_idx) {
    __shared__ float  zrow[D];
    __shared__ double rv[256];
    __shared__ int    ri[256];
    const int cnt = *ws_cnt;
    for (int r = blockIdx.x; r < cnt; r += gridDim.x) {
        const int q = ws_list[r];
        __syncthreads();
        if (threadIdx.x < D) zrow[threadIdx.x] = z[(size_t)q * D + threadIdx.x];
        __syncthreads();
        double best = 1e300;
        int    bi   = 0x7fffffff;
        for (int c = threadIdx.x; c < K_CODES; c += 256) {
            const float4* er = (const float4*)(emb + (size_t)c * D);
            double acc = 0.0;
#pragma unroll
            for (int k = 0; k < 16; ++k) {
                float4 e  = er[k];
                double d0 = (double)zrow[4 * k + 0] - (double)e.x;
                double d1 = (double)zrow[4 * k + 1] - (double)e.y;
                double d2 = (double)zrow[4 * k + 2] - (double)e.z;
                double d3 = (double)zrow[4 * k + 3] - (double)e.w;
                acc += d0 * d0 + d1 * d1 + d2 * d2 + d3 * d3;
            }
            if (acc < best) { best = acc; bi = c; }
        }
        rv[threadIdx.x] = best;
        ri[threadIdx.x] = bi;
        __syncthreads();
        for (int s = 128; s > 0; s >>= 1) {
            if (threadIdx.x < s) {
                double ov = rv[threadIdx.x + s];
                int    oi = ri[threadIdx.x + s];
                if (ov < rv[threadIdx.x] || (ov == rv[threadIdx.x] && oi < ri[threadIdx.x])) {
                    rv[threadIdx.x] = ov;
                    ri[threadIdx.x] = oi;
                }
            }
            __syncthreads();
        }
        if (threadIdx.x == 0) ws_idx[q] = ri[0];
        __syncthreads();
    }
}

// ---- K3: gather z_q, emit idx as float, per-block loss partials ----
__global__ __launch_bounds__(256) void k3_gather(const float* __restrict__ emb,
                                                 const float* __restrict__ z,
                                                 const int* __restrict__ ws_idx,
                                                 float* __restrict__ out,
                                                 float* __restrict__ partial) {
    __shared__ float sb[256];
    int g = blockIdx.x * 256 + threadIdx.x;
    int q = g >> 6, d = g & 63;
    int id = ws_idx[q];
    float e = emb[(size_t)id * D + d];
    out[g] = e;
    if (d == 0) out[(size_t)M_QUERIES * D + q] = (float)id;
    float df = e - z[g];
    sb[threadIdx.x] = df * df;
    __syncthreads();
    for (int s = 128; s > 0; s >>= 1) {
        if (threadIdx.x < s) sb[threadIdx.x] += sb[threadIdx.x + s];
        __syncthreads();
    }
    if (threadIdx.x == 0) partial[blockIdx.x] = sb[0];
}

// ---- K4: final loss reduce ----
__global__ __launch_bounds__(256) void k4_loss(const float* __restrict__ partial,
                                               float* __restrict__ out) {
    __shared__ double sb[256];
    double s = 0.0;
    for (int i = threadIdx.x; i < (M_QUERIES * D) / 256; i += 256) s += (double)partial[i];
    sb[threadIdx.x] = s;
    __syncthreads();
    for (int st = 128; st > 0; st >>= 1) {
        if (threadIdx.x < st) sb[threadIdx.x] += sb[threadIdx.x + st];
        __syncthreads();
    }
    if (threadIdx.x == 0)
        out[(size_t)M_QUERIES * D + M_QUERIES] =
            (float)(1.25 * sb[0] / (double)((size_t)M_QUERIES * D));
}

extern "C" void kernel_launch(void* const* d_in, const int* in_sizes, int n_in,
                              void* d_out, int out_size, void* d_ws, size_t ws_size,
                              hipStream_t stream) {
    const float* z   = (const float*)d_in[0];
    const float* emb = (const float*)d_in[1];
    float* out = (float*)d_out;
    char*  ws  = (char*)d_ws;

    unsigned short* e_hi    = (unsigned short*)(ws);                    // 1 MB
    unsigned short* e_lo    = (unsigned short*)(ws + 1048576);          // 1 MB
    float*          halfee  = (float*)(ws + 2097152);                   // 32 KB
    float4*         ws_part = (float4*)(ws + 2129920);                  // 2 MB
    int*            ws_idx  = (int*)(ws + 2129920 + 2097152);           // 128 KB
    int*            ws_cnt  = (int*)(ws + 2129920 + 2097152 + 131072);  // 64 B
    int*            ws_list = (int*)(ws + 2129920 + 2097152 + 131136);  // 128 KB
    float*          partial = (float*)(ws + 2129920 + 2097152 + 262208);// 32 KB

    k0_split<<<K_CODES / 4, 256, 0, stream>>>(emb, e_hi, e_lo, halfee, ws_cnt);

    dim3 g1(M_QUERIES / QPB, SLICES);
    k1_mfma<<<g1, 256, 0, stream>>>(z, e_hi, e_lo, halfee, ws_part);

    k1b_merge<<<M_QUERIES / 256, 256, 0, stream>>>(ws_part, ws_idx, ws_cnt, ws_list);

    k2_rescue<<<256, 256, 0, stream>>>(z, emb, ws_cnt, ws_list, ws_idx);

    k3_gather<<<(M_QUERIES * D) / 256, 256, 0, stream>>>(emb, z, ws_idx, out, partial);

    k4_loss<<<1, 256, 0, stream>>>(partial, out);
}

// Round 4
// 242.197 us; speedup vs baseline: 2.5946x; 1.2722x over previous
//
#include <hip/hip_runtime.h>
#include <hip/hip_bf16.h>
#include <math.h>

#define D 64
#define K_CODES 8192
#define M_QUERIES 32768
#define SLICES 4
#define CODES_PER_SLICE (K_CODES / SLICES)  // 2048
#define CHUNK 64
#define NCHUNK (CODES_PER_SLICE / CHUNK)    // 32
#define QPB 128                              // queries per block = 4 waves * 32
#define TAU_V 4e-3f                          // gap threshold in v units (d2 gap = 2*v gap)

typedef __attribute__((ext_vector_type(8))) short bf16x8;
typedef __attribute__((ext_vector_type(4))) float f32x4;

__device__ __forceinline__ unsigned short f2bf(float x) {
    __hip_bfloat16 h = __float2bfloat16(x);
    return *reinterpret_cast<unsigned short*>(&h);
}
__device__ __forceinline__ float bf2f(unsigned short s) {
    __hip_bfloat16 h;
    *reinterpret_cast<unsigned short*>(&h) = s;
    return __bfloat162float(h);
}

// ---- K0: split emb into bf16 hi/lo, he' = 0.5*||e||^2 + 128, zero counter ----
__global__ __launch_bounds__(256) void k0_split(const float* __restrict__ emb,
                                                unsigned short* __restrict__ e_hi,
                                                unsigned short* __restrict__ e_lo,
                                                float* __restrict__ halfee,
                                                int* __restrict__ ws_cnt) {
    const int wid = threadIdx.x >> 6, l = threadIdx.x & 63;
    const int c = blockIdx.x * 4 + wid;
    if (c == 0 && l == 0) *ws_cnt = 0;
    float e = emb[(size_t)c * D + l];
    unsigned short h = f2bf(e);
    float r = e - bf2f(h);
    e_hi[(size_t)c * D + l] = h;
    e_lo[(size_t)c * D + l] = f2bf(r);
    float s = e * e;
#pragma unroll
    for (int m = 1; m < 64; m <<= 1) s += __shfl_xor(s, m);
    if (l == 0) halfee[c] = 0.5f * s + 128.0f;
}

// ---- K1: MFMA scoring v = he' - z.e (bf16 split), packed top-2 argmin ----
// launch_bounds(256,2): VGPR cap 256 -> compiler lands ~112 (no spill);
// actual occupancy then 4 waves/SIMD (VGPR<=128) with LDS 33KB -> 4 blocks/CU.
__global__ __launch_bounds__(256, 2) void k1_mfma(const float* __restrict__ z,
                                                  const unsigned short* __restrict__ e_hi,
                                                  const unsigned short* __restrict__ e_lo,
                                                  const float* __restrict__ halfee,
                                                  float4* __restrict__ ws_part) {
    __shared__ unsigned short ldshi[2][CHUNK * 64];
    __shared__ unsigned short ldslo[2][CHUNK * 64];
    __shared__ float ldshe[2][CHUNK];

    const int tid = threadIdx.x;
    const int wid = tid >> 6;
    const int l   = tid & 63;
    const int l15 = l & 15, l16 = l >> 4;
    const int slice = blockIdx.y;
    const int cslice0 = slice * CODES_PER_SLICE;

    // this wave's 32 queries -> negated bf16 hi/lo B-fragments in regs
    const int qw0 = blockIdx.x * QPB + wid * 32;
    bf16x8 qh[2][2], ql[2][2];
#pragma unroll
    for (int qt = 0; qt < 2; ++qt)
#pragma unroll
        for (int kk = 0; kk < 2; ++kk) {
            const float* src = z + (size_t)(qw0 + qt * 16 + l15) * D + kk * 32 + l16 * 8;
            float4 f0 = *(const float4*)(src);
            float4 f1 = *(const float4*)(src + 4);
            float f[8] = {f0.x, f0.y, f0.z, f0.w, f1.x, f1.y, f1.z, f1.w};
            bf16x8 h, lo;
#pragma unroll
            for (int j = 0; j < 8; ++j) {
                float x = -f[j];
                unsigned short hh = f2bf(x);
                float r = x - bf2f(hh);
                h[j]  = (short)hh;
                lo[j] = (short)f2bf(r);
            }
            qh[qt][kk] = h;
            ql[qt][kk] = lo;
        }

    float g1[2] = {1e30f, 1e30f}, g2[2] = {1e30f, 1e30f};
    int   gi[2] = {0x7fffffff, 0x7fffffff};
    float4 rh[2], rl[2], rhe;

#define ISSUE_LOADS(c1)                                                          \
    {                                                                            \
        const char* bhi = (const char*)e_hi + (size_t)(cslice0 + (c1) * CHUNK) * 128; \
        const char* blo = (const char*)e_lo + (size_t)(cslice0 + (c1) * CHUNK) * 128; \
        _Pragma("unroll") for (int p = 0; p < 2; ++p) {                          \
            int idx = p * 256 + tid;                                             \
            rh[p] = *(const float4*)(bhi + idx * 16);                            \
            rl[p] = *(const float4*)(blo + idx * 16);                            \
        }                                                                        \
        if (tid < 16)                                                            \
            rhe = *(const float4*)((const char*)halfee +                         \
                                   (size_t)(cslice0 + (c1) * CHUNK) * 4 + tid * 16); \
    }

#define WRITE_LDS(buf)                                                           \
    {                                                                            \
        _Pragma("unroll") for (int p = 0; p < 2; ++p) {                          \
            int idx = p * 256 + tid;                                             \
            int r = idx >> 3, cc = idx & 7;                                      \
            int off = r * 128 + (cc ^ (r & 7)) * 16;                             \
            *(float4*)((char*)ldshi[buf] + off) = rh[p];                         \
            *(float4*)((char*)ldslo[buf] + off) = rl[p];                         \
        }                                                                        \
        if (tid < 16) *(float4*)((char*)ldshe[buf] + tid * 16) = rhe;            \
    }

#define COMPUTE(bufc, cbase)                                                     \
    {                                                                            \
        const char* bh  = (const char*)ldshi[bufc];                              \
        const char* bl  = (const char*)ldslo[bufc];                              \
        const float* bhe = ldshe[bufc];                                          \
        float m1p[2] = {1e30f, 1e30f}, m2p[2] = {1e30f, 1e30f};                  \
        _Pragma("unroll") for (int ct = 0; ct < 4; ++ct) {                       \
            int R0 = ct * 16 + l15;                                              \
            int rowb = R0 * 128;                                                 \
            int sw0 = ((l16)     ^ (R0 & 7)) * 16;                               \
            int sw1 = ((4 + l16) ^ (R0 & 7)) * 16;                               \
            bf16x8 ah0 = *(const bf16x8*)(bh + rowb + sw0);                      \
            bf16x8 ah1 = *(const bf16x8*)(bh + rowb + sw1);                      \
            bf16x8 al0 = *(const bf16x8*)(bl + rowb + sw0);                      \
            bf16x8 al1 = *(const bf16x8*)(bl + rowb + sw1);                      \
            f32x4 he = *(const f32x4*)(bhe + ct * 16 + l16 * 4);                 \
            _Pragma("unroll") for (int qt = 0; qt < 2; ++qt) {                   \
                f32x4 va;                                                        \
                va = __builtin_amdgcn_mfma_f32_16x16x32_bf16(ah0, qh[qt][0], he, 0, 0, 0); \
                va = __builtin_amdgcn_mfma_f32_16x16x32_bf16(ah1, qh[qt][1], va, 0, 0, 0); \
                va = __builtin_amdgcn_mfma_f32_16x16x32_bf16(ah0, ql[qt][0], va, 0, 0, 0); \
                va = __builtin_amdgcn_mfma_f32_16x16x32_bf16(ah1, ql[qt][1], va, 0, 0, 0); \
                va = __builtin_amdgcn_mfma_f32_16x16x32_bf16(al0, qh[qt][0], va, 0, 0, 0); \
                va = __builtin_amdgcn_mfma_f32_16x16x32_bf16(al1, qh[qt][1], va, 0, 0, 0); \
                _Pragma("unroll") for (int j = 0; j < 4; ++j) {                  \
                    int pos = ct * 4 + j;                                        \
                    float vp = __int_as_float((__float_as_int(va[j]) & 0xFFFFFFF0) | pos); \
                    m2p[qt] = __builtin_amdgcn_fmed3f(vp, m1p[qt], m2p[qt]);     \
                    m1p[qt] = fminf(m1p[qt], vp);                                \
                }                                                                \
            }                                                                    \
        }                                                                        \
        _Pragma("unroll") for (int qt = 0; qt < 2; ++qt) {                       \
            float v1 = m1p[qt];                                                  \
            int   p1 = __float_as_int(v1) & 15;                                  \
            int code = (cbase) + l16 * 4 + ((p1 >> 2) << 4) + (p1 & 3);          \
            bool lt = v1 < g1[qt];                                               \
            g2[qt] = fminf(lt ? g1[qt] : g2[qt], lt ? m2p[qt] : v1);             \
            g1[qt] = lt ? v1 : g1[qt];                                           \
            gi[qt] = lt ? code : gi[qt];                                         \
        }                                                                        \
    }

    ISSUE_LOADS(0);
    WRITE_LDS(0);
    __syncthreads();
    for (int c = 0; c < NCHUNK; ++c) {
        const int cur = c & 1;
        if (c + 1 < NCHUNK) ISSUE_LOADS(c + 1);
        COMPUTE(cur, cslice0 + c * CHUNK);
        __syncthreads();
        if (c + 1 < NCHUNK) WRITE_LDS(cur ^ 1);
        __syncthreads();
    }

    // lanes {l15, l15+16, l15+32, l15+48} share a query, hold disjoint codes
#pragma unroll
    for (int qt = 0; qt < 2; ++qt) {
        float a1 = g1[qt], a2 = g2[qt];
        int   ai = gi[qt];
#pragma unroll
        for (int mask = 16; mask <= 32; mask <<= 1) {
            float o1 = __shfl_xor(a1, mask);
            float o2 = __shfl_xor(a2, mask);
            int   oi = __shfl_xor(ai, mask);
            bool  take = (o1 < a1) || (o1 == a1 && oi < ai);
            float n2   = take ? fminf(o2, a1) : fminf(a2, o1);
            a1 = take ? o1 : a1;
            ai = take ? oi : ai;
            a2 = n2;
        }
        if (l < 16) {
            int q = qw0 + qt * 16 + l15;
            ws_part[(size_t)q * SLICES + slice] =
                make_float4(a1, a2, __int_as_float(ai), 0.f);
        }
    }
#undef ISSUE_LOADS
#undef WRITE_LDS
#undef COMPUTE
}

// ---- K1b: merge slices, flag near-ties ----
__global__ __launch_bounds__(256) void k1b_merge(const float4* __restrict__ ws_part,
                                                 int* __restrict__ ws_idx,
                                                 int* __restrict__ ws_cnt,
                                                 int* __restrict__ ws_list) {
    int q = blockIdx.x * blockDim.x + threadIdx.x;
    float m1 = 1e30f, m2 = 1e30f;
    int   i1 = 0x7fffffff;
#pragma unroll
    for (int s = 0; s < SLICES; ++s) {
        float4 p = ws_part[(size_t)q * SLICES + s];
        float v1 = p.x, v2 = p.y;
        int   vi = __float_as_int(p.z);
        if (v1 < m1 || (v1 == m1 && vi < i1)) { m2 = fminf(m1, v2); m1 = v1; i1 = vi; }
        else                                  { m2 = fminf(m2, v1); }
    }
    ws_idx[q] = i1;
    if (m2 - m1 < TAU_V) {
        int r = atomicAdd(ws_cnt, 1);
        ws_list[r] = q;
    }
}

// ---- K2: fp64 exact rescan for near-tie queries ----
__global__ __launch_bounds__(256) void k2_rescue(const float* __restrict__ z,
                                                 const float* __restrict__ emb,
                                                 const int* __restrict__ ws_cnt,
                                                 const int* __restrict__ ws_list,
                                                 int* __restrict__ ws_idx) {
    __shared__ float  zrow[D];
    __shared__ double rv[256];
    __shared__ int    ri[256];
    const int cnt = *ws_cnt;
    for (int r = blockIdx.x; r < cnt; r += gridDim.x) {
        const int q = ws_list[r];
        __syncthreads();
        if (threadIdx.x < D) zrow[threadIdx.x] = z[(size_t)q * D + threadIdx.x];
        __syncthreads();
        double best = 1e300;
        int    bi   = 0x7fffffff;
        for (int c = threadIdx.x; c < K_CODES; c += 256) {
            const float4* er = (const float4*)(emb + (size_t)c * D);
            double acc = 0.0;
#pragma unroll
            for (int k = 0; k < 16; ++k) {
                float4 e  = er[k];
                double d0 = (double)zrow[4 * k + 0] - (double)e.x;
                double d1 = (double)zrow[4 * k + 1] - (double)e.y;
                double d2 = (double)zrow[4 * k + 2] - (double)e.z;
                double d3 = (double)zrow[4 * k + 3] - (double)e.w;
                acc += d0 * d0 + d1 * d1 + d2 * d2 + d3 * d3;
            }
            if (acc < best) { best = acc; bi = c; }
        }
        rv[threadIdx.x] = best;
        ri[threadIdx.x] = bi;
        __syncthreads();
        for (int s = 128; s > 0; s >>= 1) {
            if (threadIdx.x < s) {
                double ov = rv[threadIdx.x + s];
                int    oi = ri[threadIdx.x + s];
                if (ov < rv[threadIdx.x] || (ov == rv[threadIdx.x] && oi < ri[threadIdx.x])) {
                    rv[threadIdx.x] = ov;
                    ri[threadIdx.x] = oi;
                }
            }
            __syncthreads();
        }
        if (threadIdx.x == 0) ws_idx[q] = ri[0];
        __syncthreads();
    }
}

// ---- K3: gather z_q, emit idx as float, per-block loss partials ----
__global__ __launch_bounds__(256) void k3_gather(const float* __restrict__ emb,
                                                 const float* __restrict__ z,
                                                 const int* __restrict__ ws_idx,
                                                 float* __restrict__ out,
                                                 float* __restrict__ partial) {
    __shared__ float sb[256];
    int g = blockIdx.x * 256 + threadIdx.x;
    int q = g >> 6, d = g & 63;
    int id = ws_idx[q];
    float e = emb[(size_t)id * D + d];
    out[g] = e;
    if (d == 0) out[(size_t)M_QUERIES * D + q] = (float)id;
    float df = e - z[g];
    sb[threadIdx.x] = df * df;
    __syncthreads();
    for (int s = 128; s > 0; s >>= 1) {
        if (threadIdx.x < s) sb[threadIdx.x] += sb[threadIdx.x + s];
        __syncthreads();
    }
    if (threadIdx.x == 0) partial[blockIdx.x] = sb[0];
}

// ---- K4: final loss reduce ----
__global__ __launch_bounds__(256) void k4_loss(const float* __restrict__ partial,
                                               float* __restrict__ out) {
    __shared__ double sb[256];
    double s = 0.0;
    for (int i = threadIdx.x; i < (M_QUERIES * D) / 256; i += 256) s += (double)partial[i];
    sb[threadIdx.x] = s;
    __syncthreads();
    for (int st = 128; st > 0; st >>= 1) {
        if (threadIdx.x < st) sb[threadIdx.x] += sb[threadIdx.x + st];
        __syncthreads();
    }
    if (threadIdx.x == 0)
        out[(size_t)M_QUERIES * D + M_QUERIES] =
            (float)(1.25 * sb[0] / (double)((size_t)M_QUERIES * D));
}

extern "C" void kernel_launch(void* const* d_in, const int* in_sizes, int n_in,
                              void* d_out, int out_size, void* d_ws, size_t ws_size,
                              hipStream_t stream) {
    const float* z   = (const float*)d_in[0];
    const float* emb = (const float*)d_in[1];
    float* out = (float*)d_out;
    char*  ws  = (char*)d_ws;

    unsigned short* e_hi    = (unsigned short*)(ws);                    // 1 MB
    unsigned short* e_lo    = (unsigned short*)(ws + 1048576);          // 1 MB
    float*          halfee  = (float*)(ws + 2097152);                   // 32 KB
    float4*         ws_part = (float4*)(ws + 2129920);                  // 2 MB
    int*            ws_idx  = (int*)(ws + 2129920 + 2097152);           // 128 KB
    int*            ws_cnt  = (int*)(ws + 2129920 + 2097152 + 131072);  // 64 B
    int*            ws_list = (int*)(ws + 2129920 + 2097152 + 131136);  // 128 KB
    float*          partial = (float*)(ws + 2129920 + 2097152 + 262208);// 32 KB

    k0_split<<<K_CODES / 4, 256, 0, stream>>>(emb, e_hi, e_lo, halfee, ws_cnt);

    dim3 g1(M_QUERIES / QPB, SLICES);
    k1_mfma<<<g1, 256, 0, stream>>>(z, e_hi, e_lo, halfee, ws_part);

    k1b_merge<<<M_QUERIES / 256, 256, 0, stream>>>(ws_part, ws_idx, ws_cnt, ws_list);

    k2_rescue<<<256, 256, 0, stream>>>(z, emb, ws_cnt, ws_list, ws_idx);

    k3_gather<<<(M_QUERIES * D) / 256, 256, 0, stream>>>(emb, z, ws_idx, out, partial);

    k4_loss<<<1, 256, 0, stream>>>(partial, out);
}